// Round 21
// baseline (332.818 us; speedup 1.0000x reference)
//
#include <hip/hip_runtime.h>
#include <stdint.h>

#define B_DIM 8192
#define DIN   2048
#define DOUT  8192
#define NKT   (DIN / 128)  // 16 K-tiles of 128 bytes

typedef int  v4i __attribute__((ext_vector_type(4)));
typedef char c8  __attribute__((ext_vector_type(8)));

__device__ __forceinline__ void gload_lds16(const void* g, void* l) {
  __builtin_amdgcn_global_load_lds(
      (const __attribute__((address_space(1))) void*)g,
      (__attribute__((address_space(3))) void*)l, 16, 0, 0);
}

__device__ __forceinline__ float wave_max(float m) {
#pragma unroll
  for (int off = 32; off; off >>= 1) m = fmaxf(m, __shfl_xor(m, off, 64));
  return m;
}

// ---- kernel 0: zero the two atomic absmax words ----
__global__ void k_init(unsigned int* p) {
  p[0] = 0u;
  p[1] = 0u;
}

// ---- kernel 1: global absmax of x (block-reduced, 1 atomic/block) ----
__global__ __launch_bounds__(256) void k_absmax(const float4* __restrict__ x,
                                                int n4,
                                                unsigned int* __restrict__ out_bits) {
  int idx = blockIdx.x * blockDim.x + threadIdx.x;
  int stride = gridDim.x * blockDim.x;
  float m = 0.f;
  for (int i = idx; i < n4; i += stride) {
    float4 v = x[i];
    m = fmaxf(m, fabsf(v.x));
    m = fmaxf(m, fabsf(v.y));
    m = fmaxf(m, fabsf(v.z));
    m = fmaxf(m, fabsf(v.w));
  }
  m = wave_max(m);
  __shared__ float red[4];
  if ((threadIdx.x & 63) == 0) red[threadIdx.x >> 6] = m;
  __syncthreads();
  if (threadIdx.x == 0) {
    m = fmaxf(fmaxf(red[0], red[1]), fmaxf(red[2], red[3]));
    atomicMax(out_bits, __float_as_uint(m));
  }
}

// ---- kernel 2: quantize x to int8 (8 elems/thread) ----
__global__ void k_quant_x(const float* __restrict__ x, c8* __restrict__ xq,
                          int n8, const unsigned int* __restrict__ sa_bits) {
  int i = blockIdx.x * blockDim.x + threadIdx.x;
  if (i >= n8) return;
  float s_a = __uint_as_float(*sa_bits) / 127.0f;
  const float4* p = (const float4*)(x + (size_t)i * 8);
  float4 v0 = p[0], v1 = p[1];
  float vv[8] = {v0.x, v0.y, v0.z, v0.w, v1.x, v1.y, v1.z, v1.w};
  c8 q;
#pragma unroll
  for (int j = 0; j < 8; ++j) {
    float r = fminf(fmaxf(rintf(vv[j] / s_a), -127.f), 127.f);
    q[j] = (char)(int)r;
  }
  xq[i] = q;
}

// ---- kernel 3: per-row weight absmax + quantize (1 block / row) ----
__global__ __launch_bounds__(256) void k_quant_w(const float* __restrict__ w,
                                                 c8* __restrict__ wq,
                                                 float* __restrict__ s_w) {
  int row = blockIdx.x;
  int tid = threadIdx.x;
  const float4* wr = (const float4*)(w + (size_t)row * DIN);
  float4 v0 = wr[tid * 2], v1 = wr[tid * 2 + 1];
  float vv[8] = {v0.x, v0.y, v0.z, v0.w, v1.x, v1.y, v1.z, v1.w};
  float m = 0.f;
#pragma unroll
  for (int j = 0; j < 8; ++j) m = fmaxf(m, fabsf(vv[j]));
  m = wave_max(m);
  __shared__ float wmax[4];
  if ((tid & 63) == 0) wmax[tid >> 6] = m;
  __syncthreads();
  m = fmaxf(fmaxf(wmax[0], wmax[1]), fmaxf(wmax[2], wmax[3]));
  float s = m / 127.0f;
  if (tid == 0) s_w[row] = s;
  c8 q;
#pragma unroll
  for (int j = 0; j < 8; ++j) {
    float r = fminf(fmaxf(rintf(vv[j] / s), -127.f), 127.f);
    q[j] = (char)(int)r;
  }
  wq[(size_t)row * (DIN / 8) + tid] = q;
}

// ---- kernel 4: int8 GEMM 256x256, REG-STAGED async-split (T14 / HK style) -
// R18/R20 ledger: phase pinned at 1434cyc by the global_load_lds DMA engine
// (~11.4 B/cyc/CU); LDS port (~770cyc) and MFMA (~650cyc) have headroom.
// This kernel moves staging off the DMA engine: global_load_dwordx4 -> VGPR
// (issued 1 phase early, per-wave vmcnt counting) -> ds_write_b128 -> LDS.
// ds_write+barrier is textbook LDS visibility (no R19-style cross-wave DMA
// hazard). Added LDS-port cost 16 ds_write_b128/CU/phase (~190cyc).
// WRITE calendar = R18 verbatim (WAR + read-safety audits carry over):
//   p1: B q2,q3(tau+1)  p2: A q0,q2(tau+1)  p3: A q1,q3(tau+1)
//   p4: B q0,q1(tau+2)
// LOAD calendar = write calendar shifted -1 phase; two named reg sets (sA/sB)
// alternate per phase (rule #20; 8 phases/iter keeps parity across iters).
// Per phase: load 2 units (other set); vmcnt(2) confirms prev phase's loads;
// ds_write prev set; frag reads; MFMA; lgkmcnt(0); barrier (write visibility).
// Memory map identical to R18: LDS row-major [256][128B]/op/slot, 16B-slot
// XOR swizzle via pre-swizzled SOURCE + swizzled READ; dst linear tid*16.
// Tails: kt>=NKT -> NKT-2+(kt&1): same slot, same bytes (concurrent
// identical-byte rewrite is benign).
__global__ __launch_bounds__(512) void k_gemm8(
    const char* __restrict__ Aq, const char* __restrict__ Bq,
    const float* __restrict__ s_w, const float* __restrict__ bias,
    const unsigned int* __restrict__ sa_bits, float* __restrict__ out,
    unsigned int* __restrict__ omax_bits) {
  __shared__ __align__(16) char lds[131072];

  const int tid = threadIdx.x;
  const int lane = tid & 63;
  const int wave = tid >> 6;
  const int wm = wave >> 2;  // 0..1 (M)
  const int wn = wave & 3;   // 0..3 (N)

  // bijective 2D L2-patch swizzle (R4-verified: FETCH 271->99 MB)
  const int orig = blockIdx.x;
  const int xcd = orig & 7;
  const int k = orig >> 3;
  const int bx = (xcd & 3) * 8 + (k & 7);
  const int by = (xcd >> 2) * 16 + (k >> 3);
  const int row0 = by * 256, col0 = bx * 256;

  // staging: thread t covers row_local = t>>3 (64 rows/unit), 16B slot t&7;
  // source slot pre-swizzled: global kbyte = 16*((t&7)^((t>>3)&7)).
  const size_t srcOff =
      (size_t)(tid >> 3) * DIN + 16 * ((tid & 7) ^ ((tid >> 3) & 7));
  const char* aS = Aq + (size_t)row0 * DIN + srcOff;
  const char* bS = Bq + (size_t)col0 * DIN + srcOff;

  // prologue-only DMA stage of one unit
  auto STAGE1 = [&](int kt, int isB, int q) {
    const char* src = (isB ? bS : aS) + (size_t)(q * 64) * DIN + (size_t)kt * 128;
    gload_lds16(src, &lds[(kt & 1) * 65536 + isB * 32768 + q * 8192 + tid * 16]);
  };
  // reg-staging: load one unit's 16B into a v4i
  auto LOADU = [&](int kt, int isB, int q, v4i* dst) {
    if (kt >= NKT) kt = NKT - 2 + (kt & 1);
    const char* src = (isB ? bS : aS) + (size_t)(q * 64) * DIN + (size_t)kt * 128;
    *dst = *(const v4i*)src;
  };
  // ds_write one unit's 16B from a v4i (linear dst, same bytes as R18)
  auto WRITEU = [&](int kt, int isB, int q, const v4i* v) {
    if (kt >= NKT) kt = NKT - 2 + (kt & 1);
    *(v4i*)&lds[(kt & 1) * 65536 + isB * 32768 + q * 8192 + tid * 16] = *v;
  };

  v4i acc[2][4][4];
#pragma unroll
  for (int mh = 0; mh < 2; ++mh)
#pragma unroll
    for (int mf = 0; mf < 4; ++mf)
#pragma unroll
      for (int nf = 0; nf < 4; ++nf) acc[mh][mf][nf] = (v4i){0, 0, 0, 0};

  const int fr = lane & 15;
  const int kg = lane >> 4;
  // swizzled lane part (ks=0): row-in-frag byte + 16*(kg ^ (fr&7)).
  // ks=1 flips bit 6 (slot^4): addr ^ 64.
  const int lp = fr * 128 + 16 * (kg ^ (fr & 7));
  v4i b_[4];              // persists across the (mh0, mh1) phase pair
  v4i sA0, sA1, sB0, sB1; // two staging reg sets (static names, rule #20)

// PH: LKT/LISB/LQA/LQB = this phase's LOADs (into set L0,L1);
//     WKT/WISB/WQA/WQB = this phase's ds_writes (from set W0,W1).
#define PH(SLOT, KS, MH, LKT, LISB, LQA, LQB, WKT, WISB, WQA, WQB, L0, L1,   \
           W0, W1)                                                           \
  do {                                                                       \
    LOADU(LKT, LISB, LQA, &L0);                                              \
    LOADU(LKT, LISB, LQB, &L1);                                              \
    asm volatile("s_waitcnt vmcnt(2)" ::: "memory");                         \
    WRITEU(WKT, WISB, WQA, &W0);                                             \
    WRITEU(WKT, WISB, WQB, &W1);                                             \
    v4i a_[4];                                                               \
    const int ab = (SLOT) * 65536 + wm * 16384 + (MH) * 8192 + lp;           \
    const int bb = (SLOT) * 65536 + 32768 + wn * 8192 + lp;                  \
    if (!(MH)) {                                                             \
      _Pragma("unroll") for (int nf = 0; nf < 4; ++nf) b_[nf] =              \
          *(const v4i*)&lds[(bb + nf * 2048) ^ ((KS) * 64)];                 \
    }                                                                        \
    _Pragma("unroll") for (int mf = 0; mf < 4; ++mf) a_[mf] =                \
        *(const v4i*)&lds[(ab + mf * 2048) ^ ((KS) * 64)];                   \
    _Pragma("unroll") for (int nf = 0; nf < 4; ++nf)                         \
        _Pragma("unroll") for (int mf = 0; mf < 4; ++mf) acc[MH][mf][nf] =   \
        __builtin_amdgcn_mfma_i32_16x16x64_i8(a_[mf], b_[nf],                \
                                              acc[MH][mf][nf], 0, 0, 0);     \
    asm volatile("s_waitcnt lgkmcnt(0)" ::: "memory");                       \
    __builtin_amdgcn_s_barrier();                                            \
  } while (0)

  // prologue: DMA-stage tile0 fully (8 units) + tile1's B q0,q1; reg-load
  // tile1's B q2,q3 (= load-calendar position (-1,p4)) into set A.
  // vmcnt(2): FIFO confirms the 10 DMA stages, leaves the 2 reg-loads flying.
  STAGE1(0, 0, 0);
  STAGE1(0, 0, 2);
  STAGE1(0, 0, 1);
  STAGE1(0, 0, 3);
  STAGE1(0, 1, 0);
  STAGE1(0, 1, 1);
  STAGE1(0, 1, 2);
  STAGE1(0, 1, 3);
  STAGE1(1, 1, 0);
  STAGE1(1, 1, 1);
  LOADU(1, 1, 2, &sA0);
  LOADU(1, 1, 3, &sA1);
  asm volatile("s_waitcnt vmcnt(2)" ::: "memory");
  __builtin_amdgcn_s_barrier();

#pragma unroll 1
  for (int i = 0; i < NKT / 2; ++i) {
    const int t1 = 2 * i + 1, t2 = 2 * i + 2, t3 = 2 * i + 3;
    // tile 2i (slot 0)
    PH(0, 0, 0, t1, 0, 0, 2, t1, 1, 2, 3, sB0, sB1, sA0, sA1);  // w:B23(t1)
    PH(0, 0, 1, t1, 0, 1, 3, t1, 0, 0, 2, sA0, sA1, sB0, sB1);  // w:A02(t1)
    PH(0, 1, 0, t2, 1, 0, 1, t1, 0, 1, 3, sB0, sB1, sA0, sA1);  // w:A13(t1)
    PH(0, 1, 1, t2, 1, 2, 3, t2, 1, 0, 1, sA0, sA1, sB0, sB1);  // w:B01(t2)
    // tile 2i+1 (slot 1)
    PH(1, 0, 0, t2, 0, 0, 2, t2, 1, 2, 3, sB0, sB1, sA0, sA1);  // w:B23(t2)
    PH(1, 0, 1, t2, 0, 1, 3, t2, 0, 0, 2, sA0, sA1, sB0, sB1);  // w:A02(t2)
    PH(1, 1, 0, t3, 1, 0, 1, t2, 0, 1, 3, sB0, sB1, sA0, sA1);  // w:A13(t2)
    PH(1, 1, 1, t3, 1, 2, 3, t3, 1, 0, 1, sA0, sA1, sB0, sB1);  // w:B01(t3)
  }
#undef PH

  // epilogue: out = (acc + round(bias/s_b)) * s_b, s_b = s_w[col]*s_a
  float s_a = __uint_as_float(*sa_bits) / 127.0f;
  float lmax = 0.f;
#pragma unroll
  for (int nf = 0; nf < 4; ++nf) {
    int col = col0 + wn * 64 + nf * 16 + fr;
    float sw = s_w[col];
    float sb = sw * s_a;
    float bint = rintf(bias[col] / sb);
#pragma unroll
    for (int mh = 0; mh < 2; ++mh)
#pragma unroll
      for (int mf = 0; mf < 4; ++mf) {
        int rbase = row0 + wm * 128 + mh * 64 + mf * 16 + (lane >> 4) * 4;
#pragma unroll
        for (int r = 0; r < 4; ++r) {
          float o = ((float)acc[mh][mf][nf][r] + bint) * sb;
          out[(size_t)(rbase + r) * DOUT + col] = o;
          lmax = fmaxf(lmax, fabsf(o));
        }
      }
  }
  // block-level max reduce -> 1 atomic per block
  lmax = wave_max(lmax);
  asm volatile("s_waitcnt vmcnt(0) lgkmcnt(0)" ::: "memory");  // drain tails
  __syncthreads();
  float* red = (float*)lds;
  if (lane == 0) red[wave] = lmax;
  __syncthreads();
  if (tid == 0) {
    float m = 0.f;
#pragma unroll
    for (int w2 = 0; w2 < 8; ++w2) m = fmaxf(m, red[w2]);
    atomicMax(omax_bits, __float_as_uint(m));
  }
}

// ---- kernel 5: requantize output in place ----
__global__ void k_requant(float4* __restrict__ out, int n4,
                          const unsigned int* __restrict__ omax_bits) {
  float s_o = __uint_as_float(*omax_bits) / 127.0f;
  int idx = blockIdx.x * blockDim.x + threadIdx.x;
  int stride = gridDim.x * blockDim.x;
  for (int i = idx; i < n4; i += stride) {
    float4 v = out[i];
    v.x = fminf(fmaxf(rintf(v.x / s_o), -127.f), 127.f) * s_o;
    v.y = fminf(fmaxf(rintf(v.y / s_o), -127.f), 127.f) * s_o;
    v.z = fminf(fmaxf(rintf(v.z / s_o), -127.f), 127.f) * s_o;
    v.w = fminf(fmaxf(rintf(v.w / s_o), -127.f), 127.f) * s_o;
    out[i] = v;
  }
}

extern "C" void kernel_launch(void* const* d_in, const int* in_sizes, int n_in,
                              void* d_out, int out_size, void* d_ws,
                              size_t ws_size, hipStream_t stream) {
  const float* x = (const float*)d_in[0];
  const float* w = (const float*)d_in[1];
  const float* bias = (const float*)d_in[2];
  float* out = (float*)d_out;
  char* ws = (char*)d_ws;

  unsigned int* absbits = (unsigned int*)ws;
  float* s_w = (float*)(ws + 512);
  char* xq = ws + 65536;
  char* wq = ws + 65536 + (size_t)B_DIM * DIN;

  k_init<<<1, 1, 0, stream>>>(absbits);
  k_absmax<<<1024, 256, 0, stream>>>((const float4*)x, B_DIM * DIN / 4, absbits);
  k_quant_x<<<(B_DIM * DIN / 8) / 256, 256, 0, stream>>>(x, (c8*)xq,
                                                         B_DIM * DIN / 8, absbits);
  k_quant_w<<<DOUT, 256, 0, stream>>>(w, (c8*)wq, s_w);
  k_gemm8<<<1024, 512, 0, stream>>>(xq, wq, s_w, bias, absbits, out, absbits + 1);
  k_requant<<<4096, 256, 0, stream>>>((float4*)out, B_DIM * DOUT / 4, absbits + 1);
}

// Round 22
// 327.947 us; speedup vs baseline: 1.0149x; 1.0149x over previous
//
#include <hip/hip_runtime.h>
#include <stdint.h>

#define B_DIM 8192
#define DIN   2048
#define DOUT  8192
#define NKT   (DIN / 128)  // 16 K-tiles of 128 bytes

typedef int  v4i __attribute__((ext_vector_type(4)));
typedef char c8  __attribute__((ext_vector_type(8)));

__device__ __forceinline__ void gload_lds16(const void* g, void* l) {
  __builtin_amdgcn_global_load_lds(
      (const __attribute__((address_space(1))) void*)g,
      (__attribute__((address_space(3))) void*)l, 16, 0, 0);
}

__device__ __forceinline__ float wave_max(float m) {
#pragma unroll
  for (int off = 32; off; off >>= 1) m = fmaxf(m, __shfl_xor(m, off, 64));
  return m;
}

// ---- kernel 0: zero the two atomic absmax words ----
__global__ void k_init(unsigned int* p) {
  p[0] = 0u;
  p[1] = 0u;
}

// ---- kernel 1: global absmax of x (block-reduced, 1 atomic/block) ----
__global__ __launch_bounds__(256) void k_absmax(const float4* __restrict__ x,
                                                int n4,
                                                unsigned int* __restrict__ out_bits) {
  int idx = blockIdx.x * blockDim.x + threadIdx.x;
  int stride = gridDim.x * blockDim.x;
  float m = 0.f;
  for (int i = idx; i < n4; i += stride) {
    float4 v = x[i];
    m = fmaxf(m, fabsf(v.x));
    m = fmaxf(m, fabsf(v.y));
    m = fmaxf(m, fabsf(v.z));
    m = fmaxf(m, fabsf(v.w));
  }
  m = wave_max(m);
  __shared__ float red[4];
  if ((threadIdx.x & 63) == 0) red[threadIdx.x >> 6] = m;
  __syncthreads();
  if (threadIdx.x == 0) {
    m = fmaxf(fmaxf(red[0], red[1]), fmaxf(red[2], red[3]));
    atomicMax(out_bits, __float_as_uint(m));
  }
}

// ---- kernel 2: quantize x to int8 (8 elems/thread) ----
__global__ void k_quant_x(const float* __restrict__ x, c8* __restrict__ xq,
                          int n8, const unsigned int* __restrict__ sa_bits) {
  int i = blockIdx.x * blockDim.x + threadIdx.x;
  if (i >= n8) return;
  float s_a = __uint_as_float(*sa_bits) / 127.0f;
  const float4* p = (const float4*)(x + (size_t)i * 8);
  float4 v0 = p[0], v1 = p[1];
  float vv[8] = {v0.x, v0.y, v0.z, v0.w, v1.x, v1.y, v1.z, v1.w};
  c8 q;
#pragma unroll
  for (int j = 0; j < 8; ++j) {
    float r = fminf(fmaxf(rintf(vv[j] / s_a), -127.f), 127.f);
    q[j] = (char)(int)r;
  }
  xq[i] = q;
}

// ---- kernel 3: per-row weight absmax + quantize (1 block / row) ----
__global__ __launch_bounds__(256) void k_quant_w(const float* __restrict__ w,
                                                 c8* __restrict__ wq,
                                                 float* __restrict__ s_w) {
  int row = blockIdx.x;
  int tid = threadIdx.x;
  const float4* wr = (const float4*)(w + (size_t)row * DIN);
  float4 v0 = wr[tid * 2], v1 = wr[tid * 2 + 1];
  float vv[8] = {v0.x, v0.y, v0.z, v0.w, v1.x, v1.y, v1.z, v1.w};
  float m = 0.f;
#pragma unroll
  for (int j = 0; j < 8; ++j) m = fmaxf(m, fabsf(vv[j]));
  m = wave_max(m);
  __shared__ float wmax[4];
  if ((tid & 63) == 0) wmax[tid >> 6] = m;
  __syncthreads();
  m = fmaxf(fmaxf(wmax[0], wmax[1]), fmaxf(wmax[2], wmax[3]));
  float s = m / 127.0f;
  if (tid == 0) s_w[row] = s;
  c8 q;
#pragma unroll
  for (int j = 0; j < 8; ++j) {
    float r = fminf(fmaxf(rintf(vv[j] / s), -127.f), 127.f);
    q[j] = (char)(int)r;
  }
  wq[(size_t)row * (DIN / 8) + tid] = q;
}

// ---- kernel 4: int8 GEMM 256x256, HYBRID staging (DMA for A, regs for B) --
// Ledger: R18 (all-DMA) wall 1434cyc/phase (DMA 16KB @11.4B/cyc, MFMA 650
// hidden); R21 (all-reg) wall ~1730. Different walls => different paths =>
// split: A via gload_lds DMA (8KB/phase ~717cyc), B via regload+ds_write
// (R21 mechanism at half traffic). LDS port ~500cyc, MFMA ~650.
// Calendar (R18 verbatim; tau = current tile):
//   p1: write B q2,q3(tau+1) [regs]   p2: DMA A q0,q2(tau+1)
//   p3: DMA A q1,q3(tau+1) + regload B q0,q1(tau+2)
//   p4: regload B q2,q3(next) + write B q0,q1(tau+2) [regs]
// Mixed-FIFO waits (regloads issued BEFORE same-phase DMA):
//   p1: vmcnt(0) over [A13dma x2, B23reg x2] -> confirms B23 for its write
//       (also drains A13, which is read at p3 -- 1 barrier later, safe).
//   p4: 8 outstanding [A02dma,B01reg,A13dma,B23reg] -> vmcnt(4) confirms
//       A02 (read p2', 2 barriers later) + B01 (written now).
// Cross-wave safety (R19 lesson): every DMA unit's confirm-wait is >=1
// barrier BEFORE any wave reads it. ds_write visibility: lgkmcnt(0) before
// barrier on write phases (R21-proven). WAR: every store >=1 barrier after
// its region's last read (B23@p1 after p3(t-1); B01@p4 after p3(t); A02@p2 /
// A13@p3 3 phases after last read of (t-1)).
// Memory map identical to R17/R18: LDS row-major [256][128B]/op/slot, 16B-
// slot XOR swizzle via pre-swizzled SOURCE + swizzled READ; dst tid*16.
// Tails: kt>=NKT -> NKT-2+(kt&1) (same slot, same bytes, idempotent).
__global__ __launch_bounds__(512) void k_gemm8(
    const char* __restrict__ Aq, const char* __restrict__ Bq,
    const float* __restrict__ s_w, const float* __restrict__ bias,
    const unsigned int* __restrict__ sa_bits, float* __restrict__ out,
    unsigned int* __restrict__ omax_bits) {
  __shared__ __align__(16) char lds[131072];

  const int tid = threadIdx.x;
  const int lane = tid & 63;
  const int wave = tid >> 6;
  const int wm = wave >> 2;  // 0..1 (M)
  const int wn = wave & 3;   // 0..3 (N)

  // bijective 2D L2-patch swizzle (R4-verified: FETCH 271->99 MB)
  const int orig = blockIdx.x;
  const int xcd = orig & 7;
  const int k = orig >> 3;
  const int bx = (xcd & 3) * 8 + (k & 7);
  const int by = (xcd >> 2) * 16 + (k >> 3);
  const int row0 = by * 256, col0 = bx * 256;

  // staging: thread t covers row_local = t>>3 (64 rows/unit), 16B slot t&7;
  // source slot pre-swizzled: global kbyte = 16*((t&7)^((t>>3)&7)).
  const size_t srcOff =
      (size_t)(tid >> 3) * DIN + 16 * ((tid & 7) ^ ((tid >> 3) & 7));
  const char* aS = Aq + (size_t)row0 * DIN + srcOff;
  const char* bS = Bq + (size_t)col0 * DIN + srcOff;

  // DMA-stage one (op,quarter) unit of K-tile kt (1 gload, 8KB)
  auto STAGE1 = [&](int kt, int isB, int q) {
    if (kt >= NKT) kt = NKT - 2 + (kt & 1);  // tail: same slot, same bytes
    const char* src = (isB ? bS : aS) + (size_t)(q * 64) * DIN + (size_t)kt * 128;
    gload_lds16(src, &lds[(kt & 1) * 65536 + isB * 32768 + q * 8192 + tid * 16]);
  };
  // reg-load one B unit's 16B
  auto LOADU = [&](int kt, int q, v4i* dst) {
    if (kt >= NKT) kt = NKT - 2 + (kt & 1);
    *dst = *(const v4i*)(bS + (size_t)(q * 64) * DIN + (size_t)kt * 128);
  };
  // ds_write one B unit's 16B (linear dst, same bytes as DMA would write)
  auto WRITEU = [&](int kt, int q, const v4i* v) {
    if (kt >= NKT) kt = NKT - 2 + (kt & 1);
    *(v4i*)&lds[(kt & 1) * 65536 + 32768 + q * 8192 + tid * 16] = *v;
  };

  v4i acc[2][4][4];
#pragma unroll
  for (int mh = 0; mh < 2; ++mh)
#pragma unroll
    for (int mf = 0; mf < 4; ++mf)
#pragma unroll
      for (int nf = 0; nf < 4; ++nf) acc[mh][mf][nf] = (v4i){0, 0, 0, 0};

  const int fr = lane & 15;
  const int kg = lane >> 4;
  // swizzled lane part (ks=0): row-in-frag byte + 16*(kg ^ (fr&7)).
  // ks=1 flips bit 6 (slot^4): addr ^ 64.
  const int lp = fr * 128 + 16 * (kg ^ (fr & 7));
  v4i b_[4];               // persists across the (mh0, mh1) phase pair
  v4i sX0, sX1, sY0, sY1;  // staging reg pairs (static names, rule #20)

#define READS_B(SLOT, KS)                                                    \
  do {                                                                       \
    const int bb = (SLOT) * 65536 + 32768 + wn * 8192 + lp;                  \
    _Pragma("unroll") for (int nf = 0; nf < 4; ++nf) b_[nf] =                \
        *(const v4i*)&lds[(bb + nf * 2048) ^ ((KS) * 64)];                   \
  } while (0)
#define MFMA_BLK(SLOT, KS, MH)                                               \
  do {                                                                       \
    v4i a_[4];                                                               \
    const int ab = (SLOT) * 65536 + wm * 16384 + (MH) * 8192 + lp;           \
    _Pragma("unroll") for (int mf = 0; mf < 4; ++mf) a_[mf] =                \
        *(const v4i*)&lds[(ab + mf * 2048) ^ ((KS) * 64)];                   \
    _Pragma("unroll") for (int nf = 0; nf < 4; ++nf)                         \
        _Pragma("unroll") for (int mf = 0; mf < 4; ++mf) acc[MH][mf][nf] =   \
        __builtin_amdgcn_mfma_i32_16x16x64_i8(a_[mf], b_[nf],                \
                                              acc[MH][mf][nf], 0, 0, 0);     \
  } while (0)

// p1 (KS0,MH0): confirm B23 regloads; write them; reads; MFMA; lgkm; bar
#define PH1(SLOT, WKT, W0, W1)                                               \
  do {                                                                       \
    asm volatile("s_waitcnt vmcnt(0)" ::: "memory");                         \
    WRITEU(WKT, 2, &W0);                                                     \
    WRITEU(WKT, 3, &W1);                                                     \
    READS_B(SLOT, 0);                                                        \
    MFMA_BLK(SLOT, 0, 0);                                                    \
    asm volatile("s_waitcnt lgkmcnt(0)" ::: "memory");                       \
    __builtin_amdgcn_s_barrier();                                            \
  } while (0)
// p2 (KS0,MH1): DMA A q0,q2; reads; MFMA; bar
#define PH2(SLOT, AKT)                                                       \
  do {                                                                       \
    STAGE1(AKT, 0, 0);                                                       \
    STAGE1(AKT, 0, 2);                                                       \
    MFMA_BLK(SLOT, 0, 1);                                                    \
    __builtin_amdgcn_s_barrier();                                            \
  } while (0)
// p3 (KS1,MH0): regload B q0,q1 (FIRST), DMA A q1,q3; reads; MFMA; bar
#define PH3(SLOT, LKT, L0, L1, AKT)                                          \
  do {                                                                       \
    LOADU(LKT, 0, &L0);                                                      \
    LOADU(LKT, 1, &L1);                                                      \
    STAGE1(AKT, 0, 1);                                                       \
    STAGE1(AKT, 0, 3);                                                       \
    READS_B(SLOT, 1);                                                        \
    MFMA_BLK(SLOT, 1, 0);                                                    \
    __builtin_amdgcn_s_barrier();                                            \
  } while (0)
// p4 (KS1,MH1): regload B q2,q3 (next); vmcnt(4); write B q0,q1; MFMA; bar
#define PH4(SLOT, LKT, L0, L1, WKT, W0, W1)                                  \
  do {                                                                       \
    LOADU(LKT, 2, &L0);                                                      \
    LOADU(LKT, 3, &L1);                                                      \
    asm volatile("s_waitcnt vmcnt(4)" ::: "memory");                         \
    WRITEU(WKT, 0, &W0);                                                     \
    WRITEU(WKT, 1, &W1);                                                     \
    MFMA_BLK(SLOT, 1, 1);                                                    \
    asm volatile("s_waitcnt lgkmcnt(0)" ::: "memory");                       \
    __builtin_amdgcn_s_barrier();                                            \
  } while (0)

  // prologue: DMA tile0 fully (8) + tile1's B q0,q1 (2); regload tile1's
  // B q2,q3 into sY (issued AFTER the DMAs). vmcnt(2) confirms the 10 DMAs,
  // leaves the 2 regloads in flight (confirmed at first PH1's vmcnt(0)).
  STAGE1(0, 0, 0);
  STAGE1(0, 0, 2);
  STAGE1(0, 0, 1);
  STAGE1(0, 0, 3);
  STAGE1(0, 1, 0);
  STAGE1(0, 1, 1);
  STAGE1(0, 1, 2);
  STAGE1(0, 1, 3);
  STAGE1(1, 1, 0);
  STAGE1(1, 1, 1);
  LOADU(1, 2, &sY0);
  LOADU(1, 3, &sY1);
  asm volatile("s_waitcnt vmcnt(2)" ::: "memory");
  __builtin_amdgcn_s_barrier();

#pragma unroll 1
  for (int i = 0; i < NKT / 2; ++i) {
    const int t1 = 2 * i + 1, t2 = 2 * i + 2, t3 = 2 * i + 3;
    // tile 2i (slot 0)
    PH1(0, t1, sY0, sY1);            // write B23(t1)
    PH2(0, t1);                      // DMA  A02(t1)
    PH3(0, t2, sX0, sX1, t1);        // load B01(t2); DMA A13(t1)
    PH4(0, t2, sY0, sY1, t2, sX0, sX1);  // load B23(t2); write B01(t2)
    // tile 2i+1 (slot 1)
    PH1(1, t2, sY0, sY1);            // write B23(t2)
    PH2(1, t2);                      // DMA  A02(t2)
    PH3(1, t3, sX0, sX1, t2);        // load B01(t3); DMA A13(t2)
    PH4(1, t3, sY0, sY1, t3, sX0, sX1);  // load B23(t3); write B01(t3)
  }
#undef PH1
#undef PH2
#undef PH3
#undef PH4
#undef READS_B
#undef MFMA_BLK

  // epilogue: out = (acc + round(bias/s_b)) * s_b, s_b = s_w[col]*s_a
  float s_a = __uint_as_float(*sa_bits) / 127.0f;
  float lmax = 0.f;
#pragma unroll
  for (int nf = 0; nf < 4; ++nf) {
    int col = col0 + wn * 64 + nf * 16 + fr;
    float sw = s_w[col];
    float sb = sw * s_a;
    float bint = rintf(bias[col] / sb);
#pragma unroll
    for (int mh = 0; mh < 2; ++mh)
#pragma unroll
      for (int mf = 0; mf < 4; ++mf) {
        int rbase = row0 + wm * 128 + mh * 64 + mf * 16 + (lane >> 4) * 4;
#pragma unroll
        for (int r = 0; r < 4; ++r) {
          float o = ((float)acc[mh][mf][nf][r] + bint) * sb;
          out[(size_t)(rbase + r) * DOUT + col] = o;
          lmax = fmaxf(lmax, fabsf(o));
        }
      }
  }
  // block-level max reduce -> 1 atomic per block
  lmax = wave_max(lmax);
  asm volatile("s_waitcnt vmcnt(0) lgkmcnt(0)" ::: "memory");  // drain tails
  __syncthreads();
  float* red = (float*)lds;
  if (lane == 0) red[wave] = lmax;
  __syncthreads();
  if (tid == 0) {
    float m = 0.f;
#pragma unroll
    for (int w2 = 0; w2 < 8; ++w2) m = fmaxf(m, red[w2]);
    atomicMax(omax_bits, __float_as_uint(m));
  }
}

// ---- kernel 5: requantize output in place ----
__global__ void k_requant(float4* __restrict__ out, int n4,
                          const unsigned int* __restrict__ omax_bits) {
  float s_o = __uint_as_float(*omax_bits) / 127.0f;
  int idx = blockIdx.x * blockDim.x + threadIdx.x;
  int stride = gridDim.x * blockDim.x;
  for (int i = idx; i < n4; i += stride) {
    float4 v = out[i];
    v.x = fminf(fmaxf(rintf(v.x / s_o), -127.f), 127.f) * s_o;
    v.y = fminf(fmaxf(rintf(v.y / s_o), -127.f), 127.f) * s_o;
    v.z = fminf(fmaxf(rintf(v.z / s_o), -127.f), 127.f) * s_o;
    v.w = fminf(fmaxf(rintf(v.w / s_o), -127.f), 127.f) * s_o;
    out[i] = v;
  }
}

extern "C" void kernel_launch(void* const* d_in, const int* in_sizes, int n_in,
                              void* d_out, int out_size, void* d_ws,
                              size_t ws_size, hipStream_t stream) {
  const float* x = (const float*)d_in[0];
  const float* w = (const float*)d_in[1];
  const float* bias = (const float*)d_in[2];
  float* out = (float*)d_out;
  char* ws = (char*)d_ws;

  unsigned int* absbits = (unsigned int*)ws;
  float* s_w = (float*)(ws + 512);
  char* xq = ws + 65536;
  char* wq = ws + 65536 + (size_t)B_DIM * DIN;

  k_init<<<1, 1, 0, stream>>>(absbits);
  k_absmax<<<1024, 256, 0, stream>>>((const float4*)x, B_DIM * DIN / 4, absbits);
  k_quant_x<<<(B_DIM * DIN / 8) / 256, 256, 0, stream>>>(x, (c8*)xq,
                                                         B_DIM * DIN / 8, absbits);
  k_quant_w<<<DOUT, 256, 0, stream>>>(w, (c8*)wq, s_w);
  k_gemm8<<<1024, 512, 0, stream>>>(xq, wq, s_w, bias, absbits, out, absbits + 1);
  k_requant<<<4096, 256, 0, stream>>>((float4*)out, B_DIM * DOUT / 4, absbits + 1);
}

// Round 23
// 313.237 us; speedup vs baseline: 1.0625x; 1.0470x over previous
//
#include <hip/hip_runtime.h>
#include <stdint.h>

#define B_DIM 8192
#define DIN   2048
#define DOUT  8192
#define NKT   (DIN / 128)  // 16 K-tiles of 128 bytes

typedef int  v4i __attribute__((ext_vector_type(4)));
typedef char c8  __attribute__((ext_vector_type(8)));

__device__ __forceinline__ void gload_lds16(const void* g, void* l) {
  __builtin_amdgcn_global_load_lds(
      (const __attribute__((address_space(1))) void*)g,
      (__attribute__((address_space(3))) void*)l, 16, 0, 0);
}

__device__ __forceinline__ float wave_max(float m) {
#pragma unroll
  for (int off = 32; off; off >>= 1) m = fmaxf(m, __shfl_xor(m, off, 64));
  return m;
}

// ---- kernel 0: zero the two atomic absmax words ----
__global__ void k_init(unsigned int* p) {
  p[0] = 0u;
  p[1] = 0u;
}

// ---- kernel 1: global absmax of x (block-reduced, 1 atomic/block) ----
__global__ __launch_bounds__(256) void k_absmax(const float4* __restrict__ x,
                                                int n4,
                                                unsigned int* __restrict__ out_bits) {
  int idx = blockIdx.x * blockDim.x + threadIdx.x;
  int stride = gridDim.x * blockDim.x;
  float m = 0.f;
  for (int i = idx; i < n4; i += stride) {
    float4 v = x[i];
    m = fmaxf(m, fabsf(v.x));
    m = fmaxf(m, fabsf(v.y));
    m = fmaxf(m, fabsf(v.z));
    m = fmaxf(m, fabsf(v.w));
  }
  m = wave_max(m);
  __shared__ float red[4];
  if ((threadIdx.x & 63) == 0) red[threadIdx.x >> 6] = m;
  __syncthreads();
  if (threadIdx.x == 0) {
    m = fmaxf(fmaxf(red[0], red[1]), fmaxf(red[2], red[3]));
    atomicMax(out_bits, __float_as_uint(m));
  }
}

// ---- kernel 2: quantize x to int8 (8 elems/thread) ----
__global__ void k_quant_x(const float* __restrict__ x, c8* __restrict__ xq,
                          int n8, const unsigned int* __restrict__ sa_bits) {
  int i = blockIdx.x * blockDim.x + threadIdx.x;
  if (i >= n8) return;
  float s_a = __uint_as_float(*sa_bits) / 127.0f;
  const float4* p = (const float4*)(x + (size_t)i * 8);
  float4 v0 = p[0], v1 = p[1];
  float vv[8] = {v0.x, v0.y, v0.z, v0.w, v1.x, v1.y, v1.z, v1.w};
  c8 q;
#pragma unroll
  for (int j = 0; j < 8; ++j) {
    float r = fminf(fmaxf(rintf(vv[j] / s_a), -127.f), 127.f);
    q[j] = (char)(int)r;
  }
  xq[i] = q;
}

// ---- kernel 3: per-row weight absmax + quantize (1 block / row) ----
__global__ __launch_bounds__(256) void k_quant_w(const float* __restrict__ w,
                                                 c8* __restrict__ wq,
                                                 float* __restrict__ s_w) {
  int row = blockIdx.x;
  int tid = threadIdx.x;
  const float4* wr = (const float4*)(w + (size_t)row * DIN);
  float4 v0 = wr[tid * 2], v1 = wr[tid * 2 + 1];
  float vv[8] = {v0.x, v0.y, v0.z, v0.w, v1.x, v1.y, v1.z, v1.w};
  float m = 0.f;
#pragma unroll
  for (int j = 0; j < 8; ++j) m = fmaxf(m, fabsf(vv[j]));
  m = wave_max(m);
  __shared__ float wmax[4];
  if ((tid & 63) == 0) wmax[tid >> 6] = m;
  __syncthreads();
  m = fmaxf(fmaxf(wmax[0], wmax[1]), fmaxf(wmax[2], wmax[3]));
  float s = m / 127.0f;
  if (tid == 0) s_w[row] = s;
  c8 q;
#pragma unroll
  for (int j = 0; j < 8; ++j) {
    float r = fminf(fmaxf(rintf(vv[j] / s), -127.f), 127.f);
    q[j] = (char)(int)r;
  }
  wq[(size_t)row * (DIN / 8) + tid] = q;
}

// ---- kernel 4: int8 GEMM 256x256, BURST-ISSUE staging + single drain ------
// R18 champion issues 2 gloads/phase with vmcnt(4) EVERY phase (max 6 in
// flight, 4 waits/tile, ~1 phase of landing slack). R21/R22: reg-staging in
// any mix regresses. This keeps all-DMA but changes only the CADENCE:
//   p1: issue all 4 A units of tile t+1 (4 gloads)
//   p2: issue all 4 B units of tile t+1 (4 gloads)
//   p3: (no staging)
//   p4: s_waitcnt vmcnt(0)  -- single drain; barrier -> tile t+1 visible
// Queue depth: 8 in flight from p2..p4 (vs 6); issue->confirm slack 2-3
// phases (~3000cyc >> ~900cyc of DMA work) -> the drain should be nearly
// free if the engine was cadence-limited; if it's throughput-capped at
// ~11.4 B/cyc/CU the kernel stays ~153us (then R18 is the roofline).
// Correctness is SIMPLER than R18: vmcnt(0) drain is per-wave-complete
// (no R19 counted-cross-wave subtlety); drain + barrier at (t,p4) => all
// of tile t+1 globally visible before (t+1,p1) reads.
// WAR audit: A(t+1)@(t,p1) overwrites A(t-1): A q1,q3 last read (t-1,p4),
// A q0,q2 last read (t-1,p3) -> >=1 barrier before the store issue. B(t+1)
// @(t,p2) overwrites B(t-1), last read (t-1,p4) -> 2 barriers. Reads of
// tile t: staged (t-1,p1/p2), drained (t-1,p4), barrier -> safe.
// Memory map identical to R17/R18 (verified): LDS row-major [256][128B]/op/
// slot, 16B-slot XOR swizzle (slot^=row&7) via pre-swizzled SOURCE +
// swizzled READ; full 128B-line DMA sources; dst linear tid*16.
// Tails: kt>=NKT -> NKT-2+(kt&1): same slot, same bytes (idempotent).
__global__ __launch_bounds__(512) void k_gemm8(
    const char* __restrict__ Aq, const char* __restrict__ Bq,
    const float* __restrict__ s_w, const float* __restrict__ bias,
    const unsigned int* __restrict__ sa_bits, float* __restrict__ out,
    unsigned int* __restrict__ omax_bits) {
  __shared__ __align__(16) char lds[131072];

  const int tid = threadIdx.x;
  const int lane = tid & 63;
  const int wave = tid >> 6;
  const int wm = wave >> 2;  // 0..1 (M)
  const int wn = wave & 3;   // 0..3 (N)

  // bijective 2D L2-patch swizzle (R4-verified: FETCH 271->99 MB)
  const int orig = blockIdx.x;
  const int xcd = orig & 7;
  const int k = orig >> 3;
  const int bx = (xcd & 3) * 8 + (k & 7);
  const int by = (xcd >> 2) * 16 + (k >> 3);
  const int row0 = by * 256, col0 = bx * 256;

  // staging: thread t covers row_local = t>>3 (64 rows/unit), 16B slot t&7;
  // source slot pre-swizzled: global kbyte = 16*((t&7)^((t>>3)&7)).
  const size_t srcOff =
      (size_t)(tid >> 3) * DIN + 16 * ((tid & 7) ^ ((tid >> 3) & 7));
  const char* aS = Aq + (size_t)row0 * DIN + srcOff;
  const char* bS = Bq + (size_t)col0 * DIN + srcOff;

  // stage one (op, quarter) unit of K-tile kt (1 gload, 8KB)
  auto STAGE1 = [&](int kt, int isB, int q) {
    if (kt >= NKT) kt = NKT - 2 + (kt & 1);  // tail: last same-parity tile
    const int slot = kt & 1;
    const char* src = (isB ? bS : aS) + (size_t)(q * 64) * DIN + (size_t)kt * 128;
    gload_lds16(src, &lds[slot * 65536 + isB * 32768 + q * 8192 + tid * 16]);
  };

  v4i acc[2][4][4];
#pragma unroll
  for (int mh = 0; mh < 2; ++mh)
#pragma unroll
    for (int mf = 0; mf < 4; ++mf)
#pragma unroll
      for (int nf = 0; nf < 4; ++nf) acc[mh][mf][nf] = (v4i){0, 0, 0, 0};

  const int fr = lane & 15;
  const int kg = lane >> 4;
  // swizzled lane part (ks=0): row-in-frag byte + 16*(kg ^ (fr&7)).
  // ks=1 flips bit 6 (slot^4): addr ^ 64.
  const int lp = fr * 128 + 16 * (kg ^ (fr & 7));
  v4i b_[4];  // persists across the (mh0, mh1) phase pair

#define READS_B(SLOT, KS)                                                    \
  do {                                                                       \
    const int bb = (SLOT) * 65536 + 32768 + wn * 8192 + lp;                  \
    _Pragma("unroll") for (int nf = 0; nf < 4; ++nf) b_[nf] =                \
        *(const v4i*)&lds[(bb + nf * 2048) ^ ((KS) * 64)];                   \
  } while (0)
#define MFMA_BLK(SLOT, KS, MH)                                               \
  do {                                                                       \
    v4i a_[4];                                                               \
    const int ab = (SLOT) * 65536 + wm * 16384 + (MH) * 8192 + lp;           \
    _Pragma("unroll") for (int mf = 0; mf < 4; ++mf) a_[mf] =                \
        *(const v4i*)&lds[(ab + mf * 2048) ^ ((KS) * 64)];                   \
    _Pragma("unroll") for (int nf = 0; nf < 4; ++nf)                         \
        _Pragma("unroll") for (int mf = 0; mf < 4; ++mf) acc[MH][mf][nf] =   \
        __builtin_amdgcn_mfma_i32_16x16x64_i8(a_[mf], b_[nf],                \
                                              acc[MH][mf][nf], 0, 0, 0);     \
    __builtin_amdgcn_s_barrier();                                            \
  } while (0)

  // prologue: DMA-stage tile0 fully (8 units); drain; barrier.
  STAGE1(0, 0, 0);
  STAGE1(0, 0, 1);
  STAGE1(0, 0, 2);
  STAGE1(0, 0, 3);
  STAGE1(0, 1, 0);
  STAGE1(0, 1, 1);
  STAGE1(0, 1, 2);
  STAGE1(0, 1, 3);
  asm volatile("s_waitcnt vmcnt(0)" ::: "memory");
  __builtin_amdgcn_s_barrier();

#pragma unroll 1
  for (int t = 0; t < NKT; ++t) {
    const int S = t & 1, tn = t + 1;
    // p1: issue A(t+1) x4; compute (ks0, mh0)
    STAGE1(tn, 0, 0);
    STAGE1(tn, 0, 1);
    STAGE1(tn, 0, 2);
    STAGE1(tn, 0, 3);
    READS_B(S, 0);
    MFMA_BLK(S, 0, 0);
    // p2: issue B(t+1) x4; compute (ks0, mh1)
    STAGE1(tn, 1, 0);
    STAGE1(tn, 1, 1);
    STAGE1(tn, 1, 2);
    STAGE1(tn, 1, 3);
    MFMA_BLK(S, 0, 1);
    // p3: compute (ks1, mh0)
    READS_B(S, 1);
    MFMA_BLK(S, 1, 0);
    // p4: compute (ks1, mh1); drain all DMA; barrier
    {
      v4i a_[4];
      const int ab = S * 65536 + wm * 16384 + 8192 + lp;
#pragma unroll
      for (int mf = 0; mf < 4; ++mf)
        a_[mf] = *(const v4i*)&lds[(ab + mf * 2048) ^ 64];
#pragma unroll
      for (int nf = 0; nf < 4; ++nf)
#pragma unroll
        for (int mf = 0; mf < 4; ++mf)
          acc[1][mf][nf] = __builtin_amdgcn_mfma_i32_16x16x64_i8(
              a_[mf], b_[nf], acc[1][mf][nf], 0, 0, 0);
      asm volatile("s_waitcnt vmcnt(0)" ::: "memory");
      __builtin_amdgcn_s_barrier();
    }
  }
#undef READS_B
#undef MFMA_BLK

  // epilogue: out = (acc + round(bias/s_b)) * s_b, s_b = s_w[col]*s_a
  float s_a = __uint_as_float(*sa_bits) / 127.0f;
  float lmax = 0.f;
#pragma unroll
  for (int nf = 0; nf < 4; ++nf) {
    int col = col0 + wn * 64 + nf * 16 + fr;
    float sw = s_w[col];
    float sb = sw * s_a;
    float bint = rintf(bias[col] / sb);
#pragma unroll
    for (int mh = 0; mh < 2; ++mh)
#pragma unroll
      for (int mf = 0; mf < 4; ++mf) {
        int rbase = row0 + wm * 128 + mh * 64 + mf * 16 + (lane >> 4) * 4;
#pragma unroll
        for (int r = 0; r < 4; ++r) {
          float o = ((float)acc[mh][mf][nf][r] + bint) * sb;
          out[(size_t)(rbase + r) * DOUT + col] = o;
          lmax = fmaxf(lmax, fabsf(o));
        }
      }
  }
  // block-level max reduce -> 1 atomic per block
  lmax = wave_max(lmax);
  asm volatile("s_waitcnt vmcnt(0)" ::: "memory");  // drain tail DMA into LDS
  __syncthreads();
  float* red = (float*)lds;
  if (lane == 0) red[wave] = lmax;
  __syncthreads();
  if (tid == 0) {
    float m = 0.f;
#pragma unroll
    for (int w2 = 0; w2 < 8; ++w2) m = fmaxf(m, red[w2]);
    atomicMax(omax_bits, __float_as_uint(m));
  }
}

// ---- kernel 5: requantize output in place ----
__global__ void k_requant(float4* __restrict__ out, int n4,
                          const unsigned int* __restrict__ omax_bits) {
  float s_o = __uint_as_float(*omax_bits) / 127.0f;
  int idx = blockIdx.x * blockDim.x + threadIdx.x;
  int stride = gridDim.x * blockDim.x;
  for (int i = idx; i < n4; i += stride) {
    float4 v = out[i];
    v.x = fminf(fmaxf(rintf(v.x / s_o), -127.f), 127.f) * s_o;
    v.y = fminf(fmaxf(rintf(v.y / s_o), -127.f), 127.f) * s_o;
    v.z = fminf(fmaxf(rintf(v.z / s_o), -127.f), 127.f) * s_o;
    v.w = fminf(fmaxf(rintf(v.w / s_o), -127.f), 127.f) * s_o;
    out[i] = v;
  }
}

extern "C" void kernel_launch(void* const* d_in, const int* in_sizes, int n_in,
                              void* d_out, int out_size, void* d_ws,
                              size_t ws_size, hipStream_t stream) {
  const float* x = (const float*)d_in[0];
  const float* w = (const float*)d_in[1];
  const float* bias = (const float*)d_in[2];
  float* out = (float*)d_out;
  char* ws = (char*)d_ws;

  unsigned int* absbits = (unsigned int*)ws;
  float* s_w = (float*)(ws + 512);
  char* xq = ws + 65536;
  char* wq = ws + 65536 + (size_t)B_DIM * DIN;

  k_init<<<1, 1, 0, stream>>>(absbits);
  k_absmax<<<1024, 256, 0, stream>>>((const float4*)x, B_DIM * DIN / 4, absbits);
  k_quant_x<<<(B_DIM * DIN / 8) / 256, 256, 0, stream>>>(x, (c8*)xq,
                                                         B_DIM * DIN / 8, absbits);
  k_quant_w<<<DOUT, 256, 0, stream>>>(w, (c8*)wq, s_w);
  k_gemm8<<<1024, 512, 0, stream>>>(xq, wq, s_w, bias, absbits, out, absbits + 1);
  k_requant<<<4096, 256, 0, stream>>>((float4*)out, B_DIM * DOUT / 4, absbits + 1);
}

// Round 24
// 303.704 us; speedup vs baseline: 1.0959x; 1.0314x over previous
//
#include <hip/hip_runtime.h>
#include <stdint.h>

#define B_DIM 8192
#define DIN   2048
#define DOUT  8192
#define NKT   (DIN / 128)  // 16 K-tiles of 128 bytes

typedef int  v4i __attribute__((ext_vector_type(4)));
typedef char c8  __attribute__((ext_vector_type(8)));

__device__ __forceinline__ void gload_lds16(const void* g, void* l) {
  __builtin_amdgcn_global_load_lds(
      (const __attribute__((address_space(1))) void*)g,
      (__attribute__((address_space(3))) void*)l, 16, 0, 0);
}

__device__ __forceinline__ float wave_max(float m) {
#pragma unroll
  for (int off = 32; off; off >>= 1) m = fmaxf(m, __shfl_xor(m, off, 64));
  return m;
}

// ---- kernel 0: zero the two atomic absmax words ----
__global__ void k_init(unsigned int* p) {
  p[0] = 0u;
  p[1] = 0u;
}

// ---- kernel 1: global absmax of x (block-reduced, 1 atomic/block) ----
__global__ __launch_bounds__(256) void k_absmax(const float4* __restrict__ x,
                                                int n4,
                                                unsigned int* __restrict__ out_bits) {
  int idx = blockIdx.x * blockDim.x + threadIdx.x;
  int stride = gridDim.x * blockDim.x;
  float m = 0.f;
  for (int i = idx; i < n4; i += stride) {
    float4 v = x[i];
    m = fmaxf(m, fabsf(v.x));
    m = fmaxf(m, fabsf(v.y));
    m = fmaxf(m, fabsf(v.z));
    m = fmaxf(m, fabsf(v.w));
  }
  m = wave_max(m);
  __shared__ float red[4];
  if ((threadIdx.x & 63) == 0) red[threadIdx.x >> 6] = m;
  __syncthreads();
  if (threadIdx.x == 0) {
    m = fmaxf(fmaxf(red[0], red[1]), fmaxf(red[2], red[3]));
    atomicMax(out_bits, __float_as_uint(m));
  }
}

// ---- kernel 2: quantize x to int8 (8 elems/thread) ----
__global__ void k_quant_x(const float* __restrict__ x, c8* __restrict__ xq,
                          int n8, const unsigned int* __restrict__ sa_bits) {
  int i = blockIdx.x * blockDim.x + threadIdx.x;
  if (i >= n8) return;
  float s_a = __uint_as_float(*sa_bits) / 127.0f;
  const float4* p = (const float4*)(x + (size_t)i * 8);
  float4 v0 = p[0], v1 = p[1];
  float vv[8] = {v0.x, v0.y, v0.z, v0.w, v1.x, v1.y, v1.z, v1.w};
  c8 q;
#pragma unroll
  for (int j = 0; j < 8; ++j) {
    float r = fminf(fmaxf(rintf(vv[j] / s_a), -127.f), 127.f);
    q[j] = (char)(int)r;
  }
  xq[i] = q;
}

// ---- kernel 3: per-row weight absmax + quantize (1 block / row) ----
__global__ __launch_bounds__(256) void k_quant_w(const float* __restrict__ w,
                                                 c8* __restrict__ wq,
                                                 float* __restrict__ s_w) {
  int row = blockIdx.x;
  int tid = threadIdx.x;
  const float4* wr = (const float4*)(w + (size_t)row * DIN);
  float4 v0 = wr[tid * 2], v1 = wr[tid * 2 + 1];
  float vv[8] = {v0.x, v0.y, v0.z, v0.w, v1.x, v1.y, v1.z, v1.w};
  float m = 0.f;
#pragma unroll
  for (int j = 0; j < 8; ++j) m = fmaxf(m, fabsf(vv[j]));
  m = wave_max(m);
  __shared__ float wmax[4];
  if ((tid & 63) == 0) wmax[tid >> 6] = m;
  __syncthreads();
  m = fmaxf(fmaxf(wmax[0], wmax[1]), fmaxf(wmax[2], wmax[3]));
  float s = m / 127.0f;
  if (tid == 0) s_w[row] = s;
  c8 q;
#pragma unroll
  for (int j = 0; j < 8; ++j) {
    float r = fminf(fmaxf(rintf(vv[j] / s), -127.f), 127.f);
    q[j] = (char)(int)r;
  }
  wq[(size_t)row * (DIN / 8) + tid] = q;
}

// ---- kernel 4: int8 GEMM 256x256, full-line staging, 2-PHASE DMA PIPELINE -
// CHAMPION (R18/R20, passed twice at 303.6/304.1us total; GEMM 153us,
// MfmaUtil 39.5%). Phase time closes as 16 gload_lds instrs/CU/phase x ~90cyc
// issue overhead = ~1434cyc: the per-CU DMA path is instruction-rate-capped
// (unit size already max 16B/lane). Bracketing experiments: vmcnt(6) depth-3
// races (R19, cross-wave confirm rule); burst+drain 162us (R23); reg-staged
// 185us (R21); hybrid 186us (R22) -- counted vmcnt(4), 2 units/phase is best.
// Memory map: LDS row-major [256][128B]/operand/slot, 16B-slot XOR swizzle
// (slot^=row&7); pre-swizzled SOURCE + swizzled READ (rule #21); full
// 128B-line DMA sources (8 rows x 128B per gload instruction).
// Units: (op, quarter q=64 rows) = 8KB = 1 gload/thread.
// Calendar (tau = current tile; stages issued at PHASE TOP, before reads):
//   p1: B q2,q3(tau+1)   p2: A q0,q2(tau+1)   p3: A q1,q3(tau+1)
//   p4: B q0,q1(tau+2)
// Cross-wave safety: every DMA unit's confirm-wait (vmcnt(4)) is >=1 barrier
// BEFORE any wave reads it (A units: wait@(q-1) + barrier -> read q).
// WAR: every restage >=1 barrier after its region's last read.
// Tails: kt>=NKT -> NKT-2+(kt&1): same slot, identical bytes (idempotent).
__global__ __launch_bounds__(512) void k_gemm8(
    const char* __restrict__ Aq, const char* __restrict__ Bq,
    const float* __restrict__ s_w, const float* __restrict__ bias,
    const unsigned int* __restrict__ sa_bits, float* __restrict__ out,
    unsigned int* __restrict__ omax_bits) {
  __shared__ __align__(16) char lds[131072];

  const int tid = threadIdx.x;
  const int lane = tid & 63;
  const int wave = tid >> 6;
  const int wm = wave >> 2;  // 0..1 (M)
  const int wn = wave & 3;   // 0..3 (N)

  // bijective 2D L2-patch swizzle (R4-verified: FETCH 271->99 MB)
  const int orig = blockIdx.x;
  const int xcd = orig & 7;
  const int k = orig >> 3;
  const int bx = (xcd & 3) * 8 + (k & 7);
  const int by = (xcd >> 2) * 16 + (k >> 3);
  const int row0 = by * 256, col0 = bx * 256;

  // staging: thread t covers row_local = t>>3 (64 rows/gload), 16B slot t&7;
  // source slot pre-swizzled: global kbyte = 16*((t&7)^((t>>3)&7)).
  const size_t srcOff =
      (size_t)(tid >> 3) * DIN + 16 * ((tid & 7) ^ ((tid >> 3) & 7));
  const char* aS = Aq + (size_t)row0 * DIN + srcOff;
  const char* bS = Bq + (size_t)col0 * DIN + srcOff;

  // stage one (op, quarter) unit of K-tile kt (1 gload, 8KB)
  auto STAGE1 = [&](int kt, int isB, int q) {
    if (kt >= NKT) kt = NKT - 2 + (kt & 1);  // tail: last same-parity tile
    const int slot = kt & 1;
    const char* src = (isB ? bS : aS) + (size_t)(q * 64) * DIN + (size_t)kt * 128;
    gload_lds16(src, &lds[slot * 65536 + isB * 32768 + q * 8192 + tid * 16]);
  };

  v4i acc[2][4][4];
#pragma unroll
  for (int mh = 0; mh < 2; ++mh)
#pragma unroll
    for (int mf = 0; mf < 4; ++mf)
#pragma unroll
      for (int nf = 0; nf < 4; ++nf) acc[mh][mf][nf] = (v4i){0, 0, 0, 0};

  const int fr = lane & 15;
  const int kg = lane >> 4;
  // swizzled lane part (ks=0): row-in-frag byte + 16*(kg ^ (fr&7)).
  // ks=1 flips bit 6 (slot^4): addr ^ 64.
  const int lp = fr * 128 + 16 * (kg ^ (fr & 7));
  v4i b_[4];  // persists across the (mh0, mh1) phase pair

#define PH(SLOT, KS, MH, SKT, SISB, SQA, SQB)                                \
  do {                                                                       \
    STAGE1(SKT, SISB, SQA);                                                  \
    STAGE1(SKT, SISB, SQB);                                                  \
    v4i a_[4];                                                               \
    const int ab = (SLOT) * 65536 + wm * 16384 + (MH) * 8192 + lp;           \
    const int bb = (SLOT) * 65536 + 32768 + wn * 8192 + lp;                  \
    if (!(MH)) b_[0] = *(const v4i*)&lds[bb ^ ((KS) * 64)];                  \
    _Pragma("unroll") for (int mf = 0; mf < 4; ++mf) a_[mf] =                \
        *(const v4i*)&lds[(ab + mf * 2048) ^ ((KS) * 64)];                   \
    if (!(MH)) {                                                             \
      _Pragma("unroll") for (int nf = 1; nf < 4; ++nf) b_[nf] =              \
          *(const v4i*)&lds[(bb + nf * 2048) ^ ((KS) * 64)];                 \
    }                                                                        \
    asm volatile("s_waitcnt vmcnt(4)" ::: "memory");                         \
    _Pragma("unroll") for (int nf = 0; nf < 4; ++nf)                         \
        _Pragma("unroll") for (int mf = 0; mf < 4; ++mf) acc[MH][mf][nf] =   \
        __builtin_amdgcn_mfma_i32_16x16x64_i8(a_[mf], b_[nf],                \
                                              acc[MH][mf][nf], 0, 0, 0);     \
    __builtin_amdgcn_s_barrier();                                            \
  } while (0)

  // prologue: tile0 fully (8 units) + tile1's B q0,q1 (the unit pair that
  // steady-state would have staged at (-1,p4)). vmcnt(2) confirms exactly
  // tile0's 8; tile1's pair stays in flight (confirmed by (0,p2)'s wait).
  STAGE1(0, 0, 0);
  STAGE1(0, 0, 2);
  STAGE1(0, 0, 1);
  STAGE1(0, 0, 3);
  STAGE1(0, 1, 0);
  STAGE1(0, 1, 1);
  STAGE1(0, 1, 2);
  STAGE1(0, 1, 3);
  STAGE1(1, 1, 0);
  STAGE1(1, 1, 1);
  asm volatile("s_waitcnt vmcnt(2)" ::: "memory");
  __builtin_amdgcn_s_barrier();

#pragma unroll 1
  for (int i = 0; i < NKT / 2; ++i) {
    const int t1 = 2 * i + 1, t2 = 2 * i + 2, t3 = 2 * i + 3;
    // tile 2i (slot 0)
    PH(0, 0, 0, t1, 1, 2, 3);  // p1: B q2,q3 (t1)
    PH(0, 0, 1, t1, 0, 0, 2);  // p2: A q0,q2 (t1)
    PH(0, 1, 0, t1, 0, 1, 3);  // p3: A q1,q3 (t1)
    PH(0, 1, 1, t2, 1, 0, 1);  // p4: B q0,q1 (t2)
    // tile 2i+1 (slot 1)
    PH(1, 0, 0, t2, 1, 2, 3);  // p1': B q2,q3 (t2)
    PH(1, 0, 1, t2, 0, 0, 2);  // p2': A q0,q2 (t2)
    PH(1, 1, 0, t2, 0, 1, 3);  // p3': A q1,q3 (t2)
    PH(1, 1, 1, t3, 1, 0, 1);  // p4': B q0,q1 (t3)
  }
#undef PH

  // epilogue: out = (acc + round(bias/s_b)) * s_b, s_b = s_w[col]*s_a
  float s_a = __uint_as_float(*sa_bits) / 127.0f;
  float lmax = 0.f;
#pragma unroll
  for (int nf = 0; nf < 4; ++nf) {
    int col = col0 + wn * 64 + nf * 16 + fr;
    float sw = s_w[col];
    float sb = sw * s_a;
    float bint = rintf(bias[col] / sb);
#pragma unroll
    for (int mh = 0; mh < 2; ++mh)
#pragma unroll
      for (int mf = 0; mf < 4; ++mf) {
        int rbase = row0 + wm * 128 + mh * 64 + mf * 16 + (lane >> 4) * 4;
#pragma unroll
        for (int r = 0; r < 4; ++r) {
          float o = ((float)acc[mh][mf][nf][r] + bint) * sb;
          out[(size_t)(rbase + r) * DOUT + col] = o;
          lmax = fmaxf(lmax, fabsf(o));
        }
      }
  }
  // block-level max reduce -> 1 atomic per block
  lmax = wave_max(lmax);
  asm volatile("s_waitcnt vmcnt(0)" ::: "memory");  // drain tail DMA into LDS
  __syncthreads();
  float* red = (float*)lds;
  if (lane == 0) red[wave] = lmax;
  __syncthreads();
  if (tid == 0) {
    float m = 0.f;
#pragma unroll
    for (int w2 = 0; w2 < 8; ++w2) m = fmaxf(m, red[w2]);
    atomicMax(omax_bits, __float_as_uint(m));
  }
}

// ---- kernel 5: requantize output in place ----
__global__ void k_requant(float4* __restrict__ out, int n4,
                          const unsigned int* __restrict__ omax_bits) {
  float s_o = __uint_as_float(*omax_bits) / 127.0f;
  int idx = blockIdx.x * blockDim.x + threadIdx.x;
  int stride = gridDim.x * blockDim.x;
  for (int i = idx; i < n4; i += stride) {
    float4 v = out[i];
    v.x = fminf(fmaxf(rintf(v.x / s_o), -127.f), 127.f) * s_o;
    v.y = fminf(fmaxf(rintf(v.y / s_o), -127.f), 127.f) * s_o;
    v.z = fminf(fmaxf(rintf(v.z / s_o), -127.f), 127.f) * s_o;
    v.w = fminf(fmaxf(rintf(v.w / s_o), -127.f), 127.f) * s_o;
    out[i] = v;
  }
}

extern "C" void kernel_launch(void* const* d_in, const int* in_sizes, int n_in,
                              void* d_out, int out_size, void* d_ws,
                              size_t ws_size, hipStream_t stream) {
  const float* x = (const float*)d_in[0];
  const float* w = (const float*)d_in[1];
  const float* bias = (const float*)d_in[2];
  float* out = (float*)d_out;
  char* ws = (char*)d_ws;

  unsigned int* absbits = (unsigned int*)ws;
  float* s_w = (float*)(ws + 512);
  char* xq = ws + 65536;
  char* wq = ws + 65536 + (size_t)B_DIM * DIN;

  k_init<<<1, 1, 0, stream>>>(absbits);
  k_absmax<<<1024, 256, 0, stream>>>((const float4*)x, B_DIM * DIN / 4, absbits);
  k_quant_x<<<(B_DIM * DIN / 8) / 256, 256, 0, stream>>>(x, (c8*)xq,
                                                         B_DIM * DIN / 8, absbits);
  k_quant_w<<<DOUT, 256, 0, stream>>>(w, (c8*)wq, s_w);
  k_gemm8<<<1024, 512, 0, stream>>>(xq, wq, s_w, bias, absbits, out, absbits + 1);
  k_requant<<<4096, 256, 0, stream>>>((float4*)out, B_DIM * DOUT / 4, absbits + 1);
}